// Round 14
// baseline (372.286 us; speedup 1.0000x reference)
//
#include <hip/hip_runtime.h>

#define S_LEN 2048
#define DIMSZ 3072
#define NHEAD 24
#define HDIM 128
#define NQKV 9216
#define QSCALE 0.08838834764831845f
#define FMAX 12.0f

typedef unsigned short u16;
typedef unsigned int u32;
typedef __attribute__((ext_vector_type(8))) short short8;
typedef __attribute__((ext_vector_type(4))) float f32x4;

__device__ __forceinline__ u16 f2bf(float f) {
    u32 u = __float_as_uint(f);
    u32 r = (u + 0x7fffu + ((u >> 16) & 1u)) >> 16;
    return (u16)r;
}
__device__ __forceinline__ float bf2f(u16 u) {
    return __uint_as_float((u32)u << 16);
}
__device__ __forceinline__ u32 cvtpk_bf16(float lo, float hi) {
    u32 r;
    asm("v_cvt_pk_bf16_f32 %0, %1, %2" : "=v"(r) : "v"(lo), "v"(hi));
    return r;
}

__device__ __forceinline__ void lds16(u16* lds, const u16* g) {
    __builtin_amdgcn_global_load_lds((const __attribute__((address_space(1))) u32*)g,
                                     (__attribute__((address_space(3))) u32*)lds, 16, 0, 0);
}

// ---------------- merged conversion kernel (hs, wq, wk, wv -> bf16) ----------------
__global__ void k_conv(const float4* __restrict__ hs, const float4* __restrict__ wq,
                       const float4* __restrict__ wk, const float4* __restrict__ wv,
                       u16* __restrict__ hs_b, u16* __restrict__ w_b) {
    int i = blockIdx.x * 256 + threadIdx.x;
    const float4* src;
    u16* dst;
    if (i < 1572864) { src = hs + i; dst = hs_b + (size_t)i * 4; }
    else if (i < 3932160) { src = wq + (i - 1572864); dst = w_b + (size_t)(i - 1572864) * 4; }
    else if (i < 6291456) { src = wk + (i - 3932160); dst = w_b + 9437184 + (size_t)(i - 3932160) * 4; }
    else { src = wv + (i - 6291456); dst = w_b + 18874368 + (size_t)(i - 6291456) * 4; }
    float4 v = *src;
    u32 lo = (u32)f2bf(v.x) | ((u32)f2bf(v.y) << 16);
    u32 hi = (u32)f2bf(v.z) | ((u32)f2bf(v.w) << 16);
    uint2 p; p.x = lo; p.y = hi;
    *(uint2*)dst = p;
}

// ---------------- QKV GEMM (r13 proven): tile 256x144, BK=32, grid 8x64=512, 2/CU -----
__global__ __launch_bounds__(256, 2) void k_gemm(const u16* __restrict__ A, const u16* __restrict__ W,
                                                 u16* __restrict__ C) {
    __shared__ __align__(16) u16 As[2][256 * 32]; // 16 KB each
    __shared__ __align__(16) u16 Bs[2][192 * 32]; // 12 KB each (rows 144-191 = pad)
    const int tid = threadIdx.x, wave = tid >> 6, lane = tid & 63;
    const int bm = blockIdx.x & 7, bn = blockIdx.x >> 3;
    const int frow = lane & 15, fk = lane >> 4;
    const u16* baseA = A + (size_t)(bm * 256) * DIMSZ;

    auto stageA = [&](int b, int kt) {
#pragma unroll
        for (int j = 0; j < 4; ++j) {
            int flat = j * 256 + tid, row = flat >> 2, ch = flat & 3;
            lds16(&As[b][flat * 8], baseA + (size_t)row * DIMSZ + kt * 32 + ((ch ^ ((row >> 1) & 3)) * 8));
        }
    };
    auto stageB = [&](int b, int kt) {
#pragma unroll
        for (int j = 0; j < 3; ++j) {
            int flat = j * 256 + tid, row = flat >> 2, ch = flat & 3;
            int srow = bn * 144 + row;
            srow = (srow > NQKV - 1) ? (NQKV - 1) : srow;
            lds16(&Bs[b][flat * 8], W + (size_t)srow * DIMSZ + kt * 32 + ((ch ^ ((row >> 1) & 3)) * 8));
        }
    };

    stageA(0, 0); stageB(0, 0); stageA(1, 1); stageB(1, 1);
    asm volatile("s_waitcnt vmcnt(7)");
    __builtin_amdgcn_s_barrier();

    f32x4 acc[4][9] = {};
    for (int T = 0; T < 96; ++T) {
        const int b = T & 1;
        const u16* LA = As[b];
        const u16* LB = Bs[b];
        short8 af[4], bf[9];
#pragma unroll
        for (int mf = 0; mf < 4; ++mf) {
            int row = wave * 64 + mf * 16 + frow;
            af[mf] = *(const short8*)&LA[row * 32 + ((fk ^ ((row >> 1) & 3)) * 8)];
        }
#pragma unroll
        for (int nf = 0; nf < 9; ++nf) {
            int row = nf * 16 + frow;
            bf[nf] = *(const short8*)&LB[row * 32 + ((fk ^ ((row >> 1) & 3)) * 8)];
        }
        __builtin_amdgcn_s_setprio(1);
#pragma unroll
        for (int mf = 0; mf < 4; ++mf)
#pragma unroll
            for (int nf = 0; nf < 9; ++nf)
                acc[mf][nf] = __builtin_amdgcn_mfma_f32_16x16x32_bf16(af[mf], bf[nf], acc[mf][nf], 0, 0, 0);
        __builtin_amdgcn_s_setprio(0);
        __builtin_amdgcn_s_barrier();
        if (T < 94) {
            stageA(b, T + 2); stageB(b, T + 2);
            asm volatile("s_waitcnt vmcnt(7)");
            __builtin_amdgcn_s_barrier();
        } else if (T == 94) {
            asm volatile("s_waitcnt vmcnt(0)");
            __builtin_amdgcn_s_barrier();
        }
    }

#pragma unroll
    for (int mf = 0; mf < 4; ++mf) {
#pragma unroll
        for (int nf = 0; nf < 9; ++nf) {
            int n = bn * 144 + nf * 16 + frow;
#pragma unroll
            for (int i = 0; i < 4; ++i) {
                int m = bm * 256 + wave * 64 + mf * 16 + fk * 4 + i;
                C[(size_t)m * NQKV + n] = f2bf(acc[mf][nf][i]);
            }
        }
    }
}

// ---------------- postprocess (VECTORIZED): bias + RMSNorm + RoPE + layout ------------
__global__ void k_post(const u16* __restrict__ qkv, const float* __restrict__ nw_q,
                       const float* __restrict__ nw_k, const float* __restrict__ bq,
                       const float* __restrict__ bk, const float* __restrict__ bv,
                       const float* __restrict__ cosT, const float* __restrict__ sinT,
                       u16* __restrict__ Qb, u16* __restrict__ Kb, u16* __restrict__ Vt) {
    const int tid = threadIdx.x;
    const int row = blockIdx.x * 16 + (tid >> 4);
    const int lane16 = tid & 15;
    const int s = row & 2047, h = row >> 11;
    const int d0 = lane16 * 8;
    const u16* base = qkv + (size_t)s * NQKV + h * HDIM + d0;

    float cs[8], sn[8];
    *(float4*)&cs[0] = *(const float4*)&cosT[s * HDIM + d0];
    *(float4*)&cs[4] = *(const float4*)&cosT[s * HDIM + d0 + 4];
    *(float4*)&sn[0] = *(const float4*)&sinT[s * HDIM + d0];
    *(float4*)&sn[4] = *(const float4*)&sinT[s * HDIM + d0 + 4];

    // ---- Q ----
    {
        short8 raw = *(const short8*)base;
        float b[8];
        *(float4*)&b[0] = *(const float4*)&bq[h * HDIM + d0];
        *(float4*)&b[4] = *(const float4*)&bq[h * HDIM + d0 + 4];
        float x[8], ss = 0.f;
#pragma unroll
        for (int j = 0; j < 8; ++j) { x[j] = bf2f((u16)raw[j]) + b[j]; ss += x[j] * x[j]; }
#pragma unroll
        for (int m = 1; m < 16; m <<= 1) ss += __shfl_xor(ss, m);
        float r = rsqrtf(ss * (1.0f / 128.0f) + 1e-6f);
        float w[8];
        *(float4*)&w[0] = *(const float4*)&nw_q[d0];
        *(float4*)&w[4] = *(const float4*)&nw_q[d0 + 4];
        u32 pk[4];
#pragma unroll
        for (int jp = 0; jp < 4; ++jp) {
            float e = x[2 * jp] * r * w[2 * jp];
            float o = x[2 * jp + 1] * r * w[2 * jp + 1];
            float y0 = (e * cs[2 * jp] - o * sn[2 * jp]) * QSCALE;
            float y1 = (o * cs[2 * jp] + e * sn[2 * jp]) * QSCALE;
            pk[jp] = cvtpk_bf16(y0, y1);
        }
        uint4 v; v.x = pk[0]; v.y = pk[1]; v.z = pk[2]; v.w = pk[3];
        *(uint4*)&Qb[((size_t)h * S_LEN + s) * HDIM + d0] = v;
    }
    // ---- K ----
    {
        short8 raw = *(const short8*)(base + 3072);
        float b[8];
        *(float4*)&b[0] = *(const float4*)&bk[h * HDIM + d0];
        *(float4*)&b[4] = *(const float4*)&bk[h * HDIM + d0 + 4];
        float x[8], ss = 0.f;
#pragma unroll
        for (int j = 0; j < 8; ++j) { x[j] = bf2f((u16)raw[j]) + b[j]; ss += x[j] * x[j]; }
#pragma unroll
        for (int m = 1; m < 16; m <<= 1) ss += __shfl_xor(ss, m);
        float r = rsqrtf(ss * (1.0f / 128.0f) + 1e-6f);
        float w[8];
        *(float4*)&w[0] = *(const float4*)&nw_k[d0];
        *(float4*)&w[4] = *(const float4*)&nw_k[d0 + 4];
        u32 pk[4];
#pragma unroll
        for (int jp = 0; jp < 4; ++jp) {
            float e = x[2 * jp] * r * w[2 * jp];
            float o = x[2 * jp + 1] * r * w[2 * jp + 1];
            float y0 = e * cs[2 * jp] - o * sn[2 * jp];
            float y1 = o * cs[2 * jp] + e * sn[2 * jp];
            pk[jp] = cvtpk_bf16(y0, y1);
        }
        uint4 v; v.x = pk[0]; v.y = pk[1]; v.z = pk[2]; v.w = pk[3];
        *(uint4*)&Kb[((size_t)h * S_LEN + s) * HDIM + d0] = v;
    }
    // ---- V (transposed) ----
    {
        short8 raw = *(const short8*)(base + 6144);
        float b[8];
        *(float4*)&b[0] = *(const float4*)&bv[h * HDIM + d0];
        *(float4*)&b[4] = *(const float4*)&bv[h * HDIM + d0 + 4];
#pragma unroll
        for (int j = 0; j < 8; ++j)
            Vt[((size_t)h * HDIM + d0 + j) * S_LEN + s] = f2bf(bf2f((u16)raw[j]) + b[j]);
    }
}

// ---------------- flash attention: NO K/V LDS staging (L2-resident KV, m169) ----------
// Per XCD: 3 heads pinned -> K+V = 3 MB, L2-resident; 32 qb-blocks/head run
// concurrently on the same XCD and share lines via L1/L2. kf/vf read direct from
// global (16 rows x 64B segments). LDS holds only per-wave P (4 KB). ZERO barriers
// in the kt loop; latency hidden by register deps + 8 waves/CU TLP.
__global__ __launch_bounds__(128, 2) void k_attn(const u16* __restrict__ Qb, const u16* __restrict__ Kb,
                                                 const u16* __restrict__ Vt, float* __restrict__ out) {
    __shared__ __align__(16) u16 Ps[2][32 * 32];   // per-wave P [q][key], chunk ^= (q>>2)&3
    const int tid = threadIdx.x;
    const int wave = tid >> 6, lane = tid & 63;
    const int wg = (blockIdx.x & 7) * 96 + (blockIdx.x >> 3); // XCD-major, bijective
    const int h = wg >> 5, qb = wg & 31;
    const int frow = lane & 15, fk = lane >> 4;

    short8 qf[2][4];
#pragma unroll
    for (int qg = 0; qg < 2; ++qg) {
        const u16* qbase = Qb + ((size_t)h * S_LEN + qb * 64 + wave * 32 + qg * 16 + frow) * HDIM + fk * 8;
#pragma unroll
        for (int ks = 0; ks < 4; ++ks) qf[qg][ks] = *(const short8*)(qbase + ks * 32);
    }

    const u16* Kbase = Kb + (size_t)h * S_LEN * HDIM;
    const u16* Vbase = Vt + (size_t)h * HDIM * S_LEN;

    f32x4 o[2][8] = {};
    float l_p[2] = {0.f, 0.f};

    for (int kt = 0; kt < 64; ++kt) {
        // K fragments: row = kt*32 + nf*16 + frow, 16B at (ks*4+fk)*8
        short8 kf[2][4];
#pragma unroll
        for (int nf = 0; nf < 2; ++nf)
#pragma unroll
            for (int ks = 0; ks < 4; ++ks)
                kf[nf][ks] = *(const short8*)&Kbase[(size_t)(kt * 32 + nf * 16 + frow) * HDIM + (ks * 4 + fk) * 8];
        // V fragments: row(d) = nf8*16 + frow, keys kt*32 + fk*8 (issued early; latency
        // hides under QK^T + softmax)
        short8 vf[8];
#pragma unroll
        for (int nf8 = 0; nf8 < 8; ++nf8)
            vf[nf8] = *(const short8*)&Vbase[(size_t)(nf8 * 16 + frow) * S_LEN + kt * 32 + fk * 8];

        // S^T = K Q^T
        f32x4 sacc[2][2] = {};
        __builtin_amdgcn_s_setprio(1);
#pragma unroll
        for (int nf = 0; nf < 2; ++nf)
#pragma unroll
            for (int ks = 0; ks < 4; ++ks)
#pragma unroll
                for (int qg = 0; qg < 2; ++qg)
                    sacc[qg][nf] = __builtin_amdgcn_mfma_f32_16x16x32_bf16(kf[nf][ks], qf[qg][ks], sacc[qg][nf], 0, 0, 0);
        __builtin_amdgcn_s_setprio(0);

        // fixed-max softmax: lane owns q-row qg*16+frow, keys nf*16+fk*4+{0..3}
#pragma unroll
        for (int qg = 0; qg < 2; ++qg) {
            int prow = qg * 16 + frow;
#pragma unroll
            for (int nf = 0; nf < 2; ++nf) {
                float p0 = __expf(sacc[qg][nf][0] - FMAX);
                float p1 = __expf(sacc[qg][nf][1] - FMAX);
                float p2 = __expf(sacc[qg][nf][2] - FMAX);
                float p3 = __expf(sacc[qg][nf][3] - FMAX);
                l_p[qg] += (p0 + p1) + (p2 + p3);
                uint2 pk;
                pk.x = cvtpk_bf16(p0, p1);
                pk.y = cvtpk_bf16(p2, p3);
                int c16 = (nf * 2 + (fk >> 1)) ^ ((prow >> 2) & 3);
                *(uint2*)&Ps[wave][prow * 32 + c16 * 8 + (fk & 1) * 4] = pk;
            }
        }
        // O += P V (per-wave P round-trip; lgkmcnt dep handled by compiler)
        short8 pf[2];
#pragma unroll
        for (int qg = 0; qg < 2; ++qg)
            pf[qg] = *(const short8*)&Ps[wave][(qg * 16 + frow) * 32 + ((fk ^ ((frow >> 2) & 3)) * 8)];
        __builtin_amdgcn_s_setprio(1);
#pragma unroll
        for (int nf8 = 0; nf8 < 8; ++nf8)
#pragma unroll
            for (int qg = 0; qg < 2; ++qg)
                o[qg][nf8] = __builtin_amdgcn_mfma_f32_16x16x32_bf16(pf[qg], vf[nf8], o[qg][nf8], 0, 0, 0);
        __builtin_amdgcn_s_setprio(0);
    }

#pragma unroll
    for (int qg = 0; qg < 2; ++qg) {
        l_p[qg] += __shfl_xor(l_p[qg], 16);
        l_p[qg] += __shfl_xor(l_p[qg], 32);
    }

#pragma unroll
    for (int qg = 0; qg < 2; ++qg)
#pragma unroll
        for (int i = 0; i < 4; ++i) {
            float rinv = 1.0f / __shfl(l_p[qg], fk * 4 + i);
            int srow = qb * 64 + wave * 32 + qg * 16 + fk * 4 + i;
#pragma unroll
            for (int nf8 = 0; nf8 < 8; ++nf8)
                out[(size_t)srow * DIMSZ + h * HDIM + nf8 * 16 + frow] = o[qg][nf8][i] * rinv;
        }
}

// ---------------- launch ----------------
extern "C" void kernel_launch(void* const* d_in, const int* in_sizes, int n_in,
                              void* d_out, int out_size, void* d_ws, size_t ws_size,
                              hipStream_t stream) {
    const float* hs = (const float*)d_in[0];
    const float* wq = (const float*)d_in[1];
    const float* bq = (const float*)d_in[2];
    const float* wk = (const float*)d_in[3];
    const float* bk = (const float*)d_in[4];
    const float* wv = (const float*)d_in[5];
    const float* bv = (const float*)d_in[6];
    const float* nq = (const float*)d_in[7];
    const float* nk = (const float*)d_in[8];
    const float* cosT = (const float*)d_in[9];
    const float* sinT = (const float*)d_in[10];
    float* out = (float*)d_out;

    char* ws = (char*)d_ws;
    u16* hs_b = (u16*)(ws);                      // 12,582,912
    u16* w_b = (u16*)(ws + 12582912);            // 56,623,104
    u16* qkv = (u16*)(ws + 69206016);            // 37,748,736
    u16* Qb = (u16*)(ws + 106954752);            // 12,582,912
    u16* Kb = (u16*)(ws + 119537664);            // 12,582,912
    u16* Vt = (u16*)(ws + 132120576);            // 12,582,912 -> total 144,703,488 B

    k_conv<<<dim3(33792), 256, 0, stream>>>((const float4*)hs, (const float4*)wq,
                                            (const float4*)wk, (const float4*)wv, hs_b, w_b);

    k_gemm<<<dim3(512), 256, 0, stream>>>(hs_b, w_b, qkv);

    k_post<<<dim3(3072), 256, 0, stream>>>(qkv, nq, nk, bq, bk, bv, cosT, sinT, Qb, Kb, Vt);

    k_attn<<<dim3(768), 128, 0, stream>>>(Qb, Kb, Vt, out);
}

// Round 15
// 283.050 us; speedup vs baseline: 1.3153x; 1.3153x over previous
//
#include <hip/hip_runtime.h>

#define S_LEN 2048
#define DIMSZ 3072
#define NHEAD 24
#define HDIM 128
#define NQKV 9216
#define QSCALE 0.08838834764831845f
#define FMAX 12.0f

typedef unsigned short u16;
typedef unsigned int u32;
typedef __attribute__((ext_vector_type(8))) short short8;
typedef __attribute__((ext_vector_type(4))) float f32x4;

__device__ __forceinline__ u16 f2bf(float f) {
    u32 u = __float_as_uint(f);
    u32 r = (u + 0x7fffu + ((u >> 16) & 1u)) >> 16;
    return (u16)r;
}
__device__ __forceinline__ float bf2f(u16 u) {
    return __uint_as_float((u32)u << 16);
}
__device__ __forceinline__ u32 cvtpk_bf16(float lo, float hi) {
    u32 r;
    asm("v_cvt_pk_bf16_f32 %0, %1, %2" : "=v"(r) : "v"(lo), "v"(hi));
    return r;
}

__device__ __forceinline__ void lds16(u16* lds, const u16* g) {
    __builtin_amdgcn_global_load_lds((const __attribute__((address_space(1))) u32*)g,
                                     (__attribute__((address_space(3))) u32*)lds, 16, 0, 0);
}

// ---------------- merged conversion (grid-stride, 2048 blocks per G11) ----------------
__global__ void k_conv(const float4* __restrict__ hs, const float4* __restrict__ wq,
                       const float4* __restrict__ wk, const float4* __restrict__ wv,
                       u16* __restrict__ hs_b, u16* __restrict__ w_b) {
    for (int i = blockIdx.x * 256 + threadIdx.x; i < 8650752; i += 2048 * 256) {
        const float4* src;
        u16* dst;
        if (i < 1572864) { src = hs + i; dst = hs_b + (size_t)i * 4; }
        else if (i < 3932160) { src = wq + (i - 1572864); dst = w_b + (size_t)(i - 1572864) * 4; }
        else if (i < 6291456) { src = wk + (i - 3932160); dst = w_b + 9437184 + (size_t)(i - 3932160) * 4; }
        else { src = wv + (i - 6291456); dst = w_b + 18874368 + (size_t)(i - 6291456) * 4; }
        float4 v = *src;
        u32 lo = (u32)f2bf(v.x) | ((u32)f2bf(v.y) << 16);
        u32 hi = (u32)f2bf(v.z) | ((u32)f2bf(v.w) << 16);
        uint2 p; p.x = lo; p.y = hi;
        *(uint2*)dst = p;
    }
}

// ---------------- QKV GEMM (r13 proven): tile 256x144, BK=32, grid 8x64=512, 2/CU -----
__global__ __launch_bounds__(256, 2) void k_gemm(const u16* __restrict__ A, const u16* __restrict__ W,
                                                 u16* __restrict__ C) {
    __shared__ __align__(16) u16 As[2][256 * 32]; // 16 KB each
    __shared__ __align__(16) u16 Bs[2][192 * 32]; // 12 KB each (rows 144-191 = pad)
    const int tid = threadIdx.x, wave = tid >> 6, lane = tid & 63;
    const int bm = blockIdx.x & 7, bn = blockIdx.x >> 3;
    const int frow = lane & 15, fk = lane >> 4;
    const u16* baseA = A + (size_t)(bm * 256) * DIMSZ;

    auto stageA = [&](int b, int kt) {
#pragma unroll
        for (int j = 0; j < 4; ++j) {
            int flat = j * 256 + tid, row = flat >> 2, ch = flat & 3;
            lds16(&As[b][flat * 8], baseA + (size_t)row * DIMSZ + kt * 32 + ((ch ^ ((row >> 1) & 3)) * 8));
        }
    };
    auto stageB = [&](int b, int kt) {
#pragma unroll
        for (int j = 0; j < 3; ++j) {
            int flat = j * 256 + tid, row = flat >> 2, ch = flat & 3;
            int srow = bn * 144 + row;
            srow = (srow > NQKV - 1) ? (NQKV - 1) : srow;
            lds16(&Bs[b][flat * 8], W + (size_t)srow * DIMSZ + kt * 32 + ((ch ^ ((row >> 1) & 3)) * 8));
        }
    };

    stageA(0, 0); stageB(0, 0); stageA(1, 1); stageB(1, 1);
    asm volatile("s_waitcnt vmcnt(7)");
    __builtin_amdgcn_s_barrier();

    f32x4 acc[4][9] = {};
    for (int T = 0; T < 96; ++T) {
        const int b = T & 1;
        const u16* LA = As[b];
        const u16* LB = Bs[b];
        short8 af[4], bf[9];
#pragma unroll
        for (int mf = 0; mf < 4; ++mf) {
            int row = wave * 64 + mf * 16 + frow;
            af[mf] = *(const short8*)&LA[row * 32 + ((fk ^ ((row >> 1) & 3)) * 8)];
        }
#pragma unroll
        for (int nf = 0; nf < 9; ++nf) {
            int row = nf * 16 + frow;
            bf[nf] = *(const short8*)&LB[row * 32 + ((fk ^ ((row >> 1) & 3)) * 8)];
        }
        __builtin_amdgcn_s_setprio(1);
#pragma unroll
        for (int mf = 0; mf < 4; ++mf)
#pragma unroll
            for (int nf = 0; nf < 9; ++nf)
                acc[mf][nf] = __builtin_amdgcn_mfma_f32_16x16x32_bf16(af[mf], bf[nf], acc[mf][nf], 0, 0, 0);
        __builtin_amdgcn_s_setprio(0);
        __builtin_amdgcn_s_barrier();
        if (T < 94) {
            stageA(b, T + 2); stageB(b, T + 2);
            asm volatile("s_waitcnt vmcnt(7)");
            __builtin_amdgcn_s_barrier();
        } else if (T == 94) {
            asm volatile("s_waitcnt vmcnt(0)");
            __builtin_amdgcn_s_barrier();
        }
    }

#pragma unroll
    for (int mf = 0; mf < 4; ++mf) {
#pragma unroll
        for (int nf = 0; nf < 9; ++nf) {
            int n = bn * 144 + nf * 16 + frow;
#pragma unroll
            for (int i = 0; i < 4; ++i) {
                int m = bm * 256 + wave * 64 + mf * 16 + fk * 4 + i;
                C[(size_t)m * NQKV + n] = f2bf(acc[mf][nf][i]);
            }
        }
    }
}

// ---------------- postprocess (VECTORIZED): bias + RMSNorm + RoPE + layout ------------
__global__ void k_post(const u16* __restrict__ qkv, const float* __restrict__ nw_q,
                       const float* __restrict__ nw_k, const float* __restrict__ bq,
                       const float* __restrict__ bk, const float* __restrict__ bv,
                       const float* __restrict__ cosT, const float* __restrict__ sinT,
                       u16* __restrict__ Qb, u16* __restrict__ Kb, u16* __restrict__ Vt) {
    const int tid = threadIdx.x;
    const int row = blockIdx.x * 16 + (tid >> 4);
    const int lane16 = tid & 15;
    const int s = row & 2047, h = row >> 11;
    const int d0 = lane16 * 8;
    const u16* base = qkv + (size_t)s * NQKV + h * HDIM + d0;

    float cs[8], sn[8];
    *(float4*)&cs[0] = *(const float4*)&cosT[s * HDIM + d0];
    *(float4*)&cs[4] = *(const float4*)&cosT[s * HDIM + d0 + 4];
    *(float4*)&sn[0] = *(const float4*)&sinT[s * HDIM + d0];
    *(float4*)&sn[4] = *(const float4*)&sinT[s * HDIM + d0 + 4];

    // ---- Q ----
    {
        short8 raw = *(const short8*)base;
        float b[8];
        *(float4*)&b[0] = *(const float4*)&bq[h * HDIM + d0];
        *(float4*)&b[4] = *(const float4*)&bq[h * HDIM + d0 + 4];
        float x[8], ss = 0.f;
#pragma unroll
        for (int j = 0; j < 8; ++j) { x[j] = bf2f((u16)raw[j]) + b[j]; ss += x[j] * x[j]; }
#pragma unroll
        for (int m = 1; m < 16; m <<= 1) ss += __shfl_xor(ss, m);
        float r = rsqrtf(ss * (1.0f / 128.0f) + 1e-6f);
        float w[8];
        *(float4*)&w[0] = *(const float4*)&nw_q[d0];
        *(float4*)&w[4] = *(const float4*)&nw_q[d0 + 4];
        u32 pk[4];
#pragma unroll
        for (int jp = 0; jp < 4; ++jp) {
            float e = x[2 * jp] * r * w[2 * jp];
            float o = x[2 * jp + 1] * r * w[2 * jp + 1];
            float y0 = (e * cs[2 * jp] - o * sn[2 * jp]) * QSCALE;
            float y1 = (o * cs[2 * jp] + e * sn[2 * jp]) * QSCALE;
            pk[jp] = cvtpk_bf16(y0, y1);
        }
        uint4 v; v.x = pk[0]; v.y = pk[1]; v.z = pk[2]; v.w = pk[3];
        *(uint4*)&Qb[((size_t)h * S_LEN + s) * HDIM + d0] = v;
    }
    // ---- K ----
    {
        short8 raw = *(const short8*)(base + 3072);
        float b[8];
        *(float4*)&b[0] = *(const float4*)&bk[h * HDIM + d0];
        *(float4*)&b[4] = *(const float4*)&bk[h * HDIM + d0 + 4];
        float x[8], ss = 0.f;
#pragma unroll
        for (int j = 0; j < 8; ++j) { x[j] = bf2f((u16)raw[j]) + b[j]; ss += x[j] * x[j]; }
#pragma unroll
        for (int m = 1; m < 16; m <<= 1) ss += __shfl_xor(ss, m);
        float r = rsqrtf(ss * (1.0f / 128.0f) + 1e-6f);
        float w[8];
        *(float4*)&w[0] = *(const float4*)&nw_k[d0];
        *(float4*)&w[4] = *(const float4*)&nw_k[d0 + 4];
        u32 pk[4];
#pragma unroll
        for (int jp = 0; jp < 4; ++jp) {
            float e = x[2 * jp] * r * w[2 * jp];
            float o = x[2 * jp + 1] * r * w[2 * jp + 1];
            float y0 = e * cs[2 * jp] - o * sn[2 * jp];
            float y1 = o * cs[2 * jp] + e * sn[2 * jp];
            pk[jp] = cvtpk_bf16(y0, y1);
        }
        uint4 v; v.x = pk[0]; v.y = pk[1]; v.z = pk[2]; v.w = pk[3];
        *(uint4*)&Kb[((size_t)h * S_LEN + s) * HDIM + d0] = v;
    }
    // ---- V (transposed) ----
    {
        short8 raw = *(const short8*)(base + 6144);
        float b[8];
        *(float4*)&b[0] = *(const float4*)&bv[h * HDIM + d0];
        *(float4*)&b[4] = *(const float4*)&bv[h * HDIM + d0 + 4];
#pragma unroll
        for (int j = 0; j < 8; ++j)
            Vt[((size_t)h * HDIM + d0 + j) * S_LEN + s] = f2bf(bf2f((u16)raw[j]) + b[j]);
    }
}

// ---------------- flash attention (r13 proven): staged K/V, swapped QK^T, fixed-max ---
__global__ __launch_bounds__(128, 2) void k_attn(const u16* __restrict__ Qb, const u16* __restrict__ Kb,
                                                 const u16* __restrict__ Vt, float* __restrict__ out) {
    __shared__ __align__(16) u16 Ks[2][32 * 128];  // [key][d], 16B-chunk ^= key&15
    __shared__ __align__(16) u16 Vs[2][128 * 32];  // [d][key], 16B-chunk ^= (d>>2)&3
    __shared__ __align__(16) u16 Ps[2][32 * 32];   // per-wave P [q][key], chunk ^= (q>>2)&3
    const int tid = threadIdx.x;
    const int wave = tid >> 6, lane = tid & 63;
    const int wg = (blockIdx.x & 7) * 96 + (blockIdx.x >> 3); // XCD-major, bijective
    const int h = wg >> 5, qb = wg & 31;
    const int frow = lane & 15, fk = lane >> 4;

    short8 qf[2][4];
#pragma unroll
    for (int qg = 0; qg < 2; ++qg) {
        const u16* qbase = Qb + ((size_t)h * S_LEN + qb * 64 + wave * 32 + qg * 16 + frow) * HDIM + fk * 8;
#pragma unroll
        for (int ks = 0; ks < 4; ++ks) qf[qg][ks] = *(const short8*)(qbase + ks * 32);
    }

    f32x4 o[2][8] = {};
    float l_p[2] = {0.f, 0.f};

#define STAGE(buf, kt)                                                                        \
    {                                                                                         \
        _Pragma("unroll") for (int c = 0; c < 4; ++c) {                                       \
            int flat = c * 128 + tid;                                                         \
            int r = flat >> 4, ch = flat & 15;                                                \
            lds16(Ks[buf] + flat * 8,                                                         \
                  Kb + ((size_t)h * S_LEN + (kt) * 32 + r) * HDIM + ((ch ^ (r & 15)) * 8));   \
        }                                                                                     \
        _Pragma("unroll") for (int c = 0; c < 4; ++c) {                                       \
            int flat = c * 128 + tid;                                                         \
            int r = flat >> 2, ch = flat & 3;                                                 \
            lds16(Vs[buf] + flat * 8,                                                         \
                  Vt + ((size_t)h * HDIM + r) * S_LEN + (kt) * 32 + ((ch ^ ((r >> 2) & 3)) * 8)); \
        }                                                                                     \
    }

    STAGE(0, 0);
    __syncthreads();
    int cur = 0;

    for (int kt = 0; kt < 64; ++kt) {
        if (kt + 1 < 64) STAGE(cur ^ 1, kt + 1);
        f32x4 sacc[2][2] = {};
        __builtin_amdgcn_s_setprio(1);
#pragma unroll
        for (int nf = 0; nf < 2; ++nf) {
#pragma unroll
            for (int ks = 0; ks < 4; ++ks) {
                short8 kf = *(const short8*)&Ks[cur][(nf * 16 + frow) * 128 + (((ks * 4 + fk) ^ frow) * 8)];
#pragma unroll
                for (int qg = 0; qg < 2; ++qg)
                    sacc[qg][nf] = __builtin_amdgcn_mfma_f32_16x16x32_bf16(kf, qf[qg][ks], sacc[qg][nf], 0, 0, 0);
            }
        }
        __builtin_amdgcn_s_setprio(0);
#pragma unroll
        for (int qg = 0; qg < 2; ++qg) {
            int prow = qg * 16 + frow;
#pragma unroll
            for (int nf = 0; nf < 2; ++nf) {
                float p0 = __expf(sacc[qg][nf][0] - FMAX);
                float p1 = __expf(sacc[qg][nf][1] - FMAX);
                float p2 = __expf(sacc[qg][nf][2] - FMAX);
                float p3 = __expf(sacc[qg][nf][3] - FMAX);
                l_p[qg] += (p0 + p1) + (p2 + p3);
                uint2 pk;
                pk.x = cvtpk_bf16(p0, p1);
                pk.y = cvtpk_bf16(p2, p3);
                int c16 = (nf * 2 + (fk >> 1)) ^ ((prow >> 2) & 3);
                *(uint2*)&Ps[wave][prow * 32 + c16 * 8 + (fk & 1) * 4] = pk;
            }
        }
        short8 pf[2];
#pragma unroll
        for (int qg = 0; qg < 2; ++qg)
            pf[qg] = *(const short8*)&Ps[wave][(qg * 16 + frow) * 32 + ((fk ^ ((frow >> 2) & 3)) * 8)];
        __builtin_amdgcn_s_setprio(1);
#pragma unroll
        for (int nf8 = 0; nf8 < 8; ++nf8) {
            short8 vf = *(const short8*)&Vs[cur][(nf8 * 16 + frow) * 32 + ((fk ^ ((frow >> 2) & 3)) * 8)];
#pragma unroll
            for (int qg = 0; qg < 2; ++qg)
                o[qg][nf8] = __builtin_amdgcn_mfma_f32_16x16x32_bf16(pf[qg], vf, o[qg][nf8], 0, 0, 0);
        }
        __builtin_amdgcn_s_setprio(0);
        __syncthreads();
        cur ^= 1;
    }
#undef STAGE

#pragma unroll
    for (int qg = 0; qg < 2; ++qg) {
        l_p[qg] += __shfl_xor(l_p[qg], 16);
        l_p[qg] += __shfl_xor(l_p[qg], 32);
    }

#pragma unroll
    for (int qg = 0; qg < 2; ++qg)
#pragma unroll
        for (int i = 0; i < 4; ++i) {
            float rinv = 1.0f / __shfl(l_p[qg], fk * 4 + i);
            int srow = qb * 64 + wave * 32 + qg * 16 + fk * 4 + i;
#pragma unroll
            for (int nf8 = 0; nf8 < 8; ++nf8)
                out[(size_t)srow * DIMSZ + h * HDIM + nf8 * 16 + frow] = o[qg][nf8][i] * rinv;
        }
}

// ---------------- launch ----------------
extern "C" void kernel_launch(void* const* d_in, const int* in_sizes, int n_in,
                              void* d_out, int out_size, void* d_ws, size_t ws_size,
                              hipStream_t stream) {
    const float* hs = (const float*)d_in[0];
    const float* wq = (const float*)d_in[1];
    const float* bq = (const float*)d_in[2];
    const float* wk = (const float*)d_in[3];
    const float* bk = (const float*)d_in[4];
    const float* wv = (const float*)d_in[5];
    const float* bv = (const float*)d_in[6];
    const float* nq = (const float*)d_in[7];
    const float* nk = (const float*)d_in[8];
    const float* cosT = (const float*)d_in[9];
    const float* sinT = (const float*)d_in[10];
    float* out = (float*)d_out;

    char* ws = (char*)d_ws;
    u16* hs_b = (u16*)(ws);                      // 12,582,912
    u16* w_b = (u16*)(ws + 12582912);            // 56,623,104
    u16* qkv = (u16*)(ws + 69206016);            // 37,748,736
    u16* Qb = (u16*)(ws + 106954752);            // 12,582,912
    u16* Kb = (u16*)(ws + 119537664);            // 12,582,912
    u16* Vt = (u16*)(ws + 132120576);            // 12,582,912 -> total 144,703,488 B

    k_conv<<<dim3(2048), 256, 0, stream>>>((const float4*)hs, (const float4*)wq,
                                           (const float4*)wk, (const float4*)wv, hs_b, w_b);

    k_gemm<<<dim3(512), 256, 0, stream>>>(hs_b, w_b, qkv);

    k_post<<<dim3(3072), 256, 0, stream>>>(qkv, nq, nk, bq, bk, bv, cosT, sinT, Qb, Kb, Vt);

    k_attn<<<dim3(768), 128, 0, stream>>>(Qb, Kb, Vt, out);
}